// Round 1
// baseline (2384.622 us; speedup 1.0000x reference)
//
#include <hip/hip_runtime.h>
#include <hip/hip_bf16.h>
#include <cstdint>
#include <cstddef>

#define T_TOK 4096
#define DM 1024
#define DFF 4096
#define NE 8
#define BT 64
#define PADCAP (T_TOK * 2 + NE * BT) /* 8704: every bucket padded to 64 */
#define MTILES (PADCAP / BT)         /* 136 */

// ---------------- gating: one wave per token ----------------
__global__ __launch_bounds__(256) void gate_kernel(
    const float* __restrict__ x, const float* __restrict__ Wg,
    int* __restrict__ counts, int* __restrict__ topk_idx,
    float* __restrict__ topk_w) {
  int gid = blockIdx.x * blockDim.x + threadIdx.x;
  int t = gid >> 6;
  int lane = gid & 63;
  if (t >= T_TOK) return;
  const float* xr = x + (size_t)t * DM;
  float acc[NE];
#pragma unroll
  for (int e = 0; e < NE; ++e) acc[e] = 0.f;
#pragma unroll
  for (int j = 0; j < DM / 64; ++j) {
    int d = lane + j * 64;
    float xv = xr[d];
    const float4* wr = (const float4*)(Wg + (size_t)d * NE);
    float4 w0 = wr[0], w1 = wr[1];
    acc[0] += xv * w0.x; acc[1] += xv * w0.y;
    acc[2] += xv * w0.z; acc[3] += xv * w0.w;
    acc[4] += xv * w1.x; acc[5] += xv * w1.y;
    acc[6] += xv * w1.z; acc[7] += xv * w1.w;
  }
#pragma unroll
  for (int off = 32; off >= 1; off >>= 1) {
#pragma unroll
    for (int e = 0; e < NE; ++e) acc[e] += __shfl_xor(acc[e], off, 64);
  }
  if (lane == 0) {
    int i0 = 0;
#pragma unroll
    for (int e = 1; e < NE; ++e)
      if (acc[e] > acc[i0]) i0 = e;  // strict > keeps lowest index on ties (jax semantics)
    int i1 = (i0 == 0) ? 1 : 0;
#pragma unroll
    for (int e = 0; e < NE; ++e)
      if (e != i0 && acc[e] > acc[i1]) i1 = e;
    // renormalized top-2 softmax == softmax over the 2 selected logits
    float e1 = __expf(acc[i1] - acc[i0]);
    float inv = 1.f / (1.f + e1);
    topk_idx[t * 2] = i0;
    topk_idx[t * 2 + 1] = i1;
    topk_w[t * 2] = inv;
    topk_w[t * 2 + 1] = e1 * inv;
    atomicAdd(&counts[i0], 1);
    atomicAdd(&counts[i1], 1);
  }
}

// ---------------- routing bookkeeping ----------------
__global__ void init_kernel(int* counts, int* cursors, int* bucket_tok) {
  int i = blockIdx.x * blockDim.x + threadIdx.x;
  if (i < NE) { counts[i] = 0; cursors[i] = 0; }
  if (i < PADCAP) bucket_tok[i] = -1;
}

__global__ void offsets_kernel(const int* __restrict__ counts,
                               int* __restrict__ offsets) {
  if (threadIdx.x == 0) {
    int o = 0;
    offsets[0] = 0;
    for (int e = 0; e < NE; ++e) {
      o += (counts[e] + BT - 1) & ~(BT - 1);  // pad each bucket to 64
      offsets[e + 1] = o;
    }
  }
}

__global__ void scatter_kernel(const int* __restrict__ topk_idx,
                               const float* __restrict__ topk_w,
                               const int* __restrict__ offsets,
                               int* __restrict__ cursors,
                               int* __restrict__ bucket_tok,
                               float* __restrict__ bucket_w) {
  int t = blockIdx.x * blockDim.x + threadIdx.x;
  if (t >= T_TOK) return;
#pragma unroll
  for (int k = 0; k < 2; ++k) {
    int e = topk_idx[t * 2 + k];
    float w = topk_w[t * 2 + k];
    int pos = atomicAdd(&cursors[e], 1);
    int slot = offsets[e] + pos;
    bucket_tok[slot] = t;
    bucket_w[slot] = w;
  }
}

// ---------------- GEMM1: h = relu(gather(x) @ W1e + b1e) ----------------
__global__ __launch_bounds__(256) void gemm1_kernel(
    const float* __restrict__ x, const float* __restrict__ W1,
    const float* __restrict__ b1, const int* __restrict__ offsets,
    const int* __restrict__ bucket_tok, __hip_bfloat16* __restrict__ h) {
  int r0 = blockIdx.x * BT;
  if (r0 >= offsets[NE]) return;
  int e = 0;
  while (offsets[e + 1] <= r0) ++e;

  __shared__ __align__(16) float As[16][BT + 4];  // +4: kills 16-way write conflict
  __shared__ __align__(16) float Bs[16][BT];
  __shared__ int toks[BT];
  int tid = threadIdx.x;
  if (tid < BT) toks[tid] = bucket_tok[r0 + tid];
  __syncthreads();

  const float* W1e = W1 + (size_t)e * DM * DFF;
  int n0 = blockIdx.y * BT;
  int tx = tid & 15, ty = tid >> 4;
  float acc[4][4] = {};

  for (int k0 = 0; k0 < DM; k0 += 16) {
#pragma unroll
    for (int i = 0; i < 4; ++i) {
      int li = tid + i * 256;
      int m = li >> 4, kk = li & 15;
      int tk = toks[m];
      As[kk][m] = (tk >= 0) ? x[(size_t)tk * DM + k0 + kk] : 0.f;
    }
#pragma unroll
    for (int i = 0; i < 4; ++i) {
      int li = tid + i * 256;
      int kk = li >> 6, nn = li & 63;
      Bs[kk][nn] = W1e[(size_t)(k0 + kk) * DFF + n0 + nn];
    }
    __syncthreads();
#pragma unroll
    for (int kk = 0; kk < 16; ++kk) {
      float4 a = *(const float4*)&As[kk][ty * 4];
      float4 b = *(const float4*)&Bs[kk][tx * 4];
      float av[4] = {a.x, a.y, a.z, a.w};
      float bv[4] = {b.x, b.y, b.z, b.w};
#pragma unroll
      for (int i = 0; i < 4; ++i)
#pragma unroll
        for (int j = 0; j < 4; ++j) acc[i][j] += av[i] * bv[j];
    }
    __syncthreads();
  }

  const float* b1e = b1 + (size_t)e * DFF;
#pragma unroll
  for (int i = 0; i < 4; ++i) {
    int m = ty * 4 + i;
    size_t row = (size_t)(r0 + m) * DFF + n0;
#pragma unroll
    for (int j = 0; j < 4; ++j) {
      int n = tx * 4 + j;
      float v = acc[i][j] + b1e[n0 + n];
      h[row + n] = __float2bfloat16(fmaxf(v, 0.f));
    }
  }
}

// ---------------- GEMM2: out += w * (h @ W2e + b2e) ----------------
__global__ __launch_bounds__(256) void gemm2_kernel(
    const __hip_bfloat16* __restrict__ h, const float* __restrict__ W2,
    const float* __restrict__ b2, const int* __restrict__ offsets,
    const int* __restrict__ bucket_tok, const float* __restrict__ bucket_w,
    float* __restrict__ out) {
  int r0 = blockIdx.x * BT;
  if (r0 >= offsets[NE]) return;
  int e = 0;
  while (offsets[e + 1] <= r0) ++e;

  __shared__ __align__(16) float As[16][BT + 4];
  __shared__ __align__(16) float Bs[16][BT];
  __shared__ int toks[BT];
  __shared__ float wts[BT];
  int tid = threadIdx.x;
  if (tid < BT) {
    toks[tid] = bucket_tok[r0 + tid];
    wts[tid] = bucket_w[r0 + tid];
  }
  __syncthreads();

  const float* W2e = W2 + (size_t)e * DFF * DM;
  int n0 = blockIdx.y * BT;
  int tx = tid & 15, ty = tid >> 4;
  float acc[4][4] = {};

  for (int k0 = 0; k0 < DFF; k0 += 16) {
#pragma unroll
    for (int i = 0; i < 4; ++i) {
      int li = tid + i * 256;
      int m = li >> 4, kk = li & 15;
      As[kk][m] = __bfloat162float(h[(size_t)(r0 + m) * DFF + k0 + kk]);
    }
#pragma unroll
    for (int i = 0; i < 4; ++i) {
      int li = tid + i * 256;
      int kk = li >> 6, nn = li & 63;
      Bs[kk][nn] = W2e[(size_t)(k0 + kk) * DM + n0 + nn];
    }
    __syncthreads();
#pragma unroll
    for (int kk = 0; kk < 16; ++kk) {
      float4 a = *(const float4*)&As[kk][ty * 4];
      float4 b = *(const float4*)&Bs[kk][tx * 4];
      float av[4] = {a.x, a.y, a.z, a.w};
      float bv[4] = {b.x, b.y, b.z, b.w};
#pragma unroll
      for (int i = 0; i < 4; ++i)
#pragma unroll
        for (int j = 0; j < 4; ++j) acc[i][j] += av[i] * bv[j];
    }
    __syncthreads();
  }

  const float* b2e = b2 + (size_t)e * DM;
#pragma unroll
  for (int i = 0; i < 4; ++i) {
    int m = ty * 4 + i;
    int tk = toks[m];
    if (tk < 0) continue;
    float w = wts[m];
#pragma unroll
    for (int j = 0; j < 4; ++j) {
      int n = n0 + tx * 4 + j;
      atomicAdd(&out[(size_t)tk * DM + n], (acc[i][j] + b2e[n]) * w);
    }
  }
}

extern "C" void kernel_launch(void* const* d_in, const int* in_sizes, int n_in,
                              void* d_out, int out_size, void* d_ws,
                              size_t ws_size, hipStream_t stream) {
  const float* x = (const float*)d_in[0];
  const float* Wg = (const float*)d_in[1];
  const float* W1 = (const float*)d_in[2];
  const float* b1 = (const float*)d_in[3];
  const float* W2 = (const float*)d_in[4];
  const float* b2 = (const float*)d_in[5];
  float* out = (float*)d_out;

  // workspace layout (ints): [0:8) counts | [8:17) offsets | [20:28) cursors |
  // [32:32+8704) bucket_tok | then bucket_w, topk_idx, topk_w; h at 256 KiB.
  int* ws_i = (int*)d_ws;
  int* counts = ws_i;
  int* offsets = ws_i + 8;
  int* cursors = ws_i + 20;
  int* bucket_tok = ws_i + 32;
  float* bucket_w = (float*)(ws_i + 32 + PADCAP);
  int* topk_idx = ws_i + 32 + 2 * PADCAP;
  float* topk_w = (float*)(ws_i + 32 + 2 * PADCAP + 2 * T_TOK);
  __hip_bfloat16* h = (__hip_bfloat16*)((char*)d_ws + (1 << 18));

  hipMemsetAsync(d_out, 0, (size_t)T_TOK * DM * sizeof(float), stream);
  init_kernel<<<(PADCAP + 255) / 256, 256, 0, stream>>>(counts, cursors,
                                                        bucket_tok);
  gate_kernel<<<T_TOK / 4, 256, 0, stream>>>(x, Wg, counts, topk_idx, topk_w);
  offsets_kernel<<<1, 64, 0, stream>>>(counts, offsets);
  scatter_kernel<<<T_TOK / 256, 256, 0, stream>>>(topk_idx, topk_w, offsets,
                                                  cursors, bucket_tok, bucket_w);
  gemm1_kernel<<<dim3(MTILES, DFF / BT), 256, 0, stream>>>(x, W1, b1, offsets,
                                                           bucket_tok, h);
  gemm2_kernel<<<dim3(MTILES, DM / BT), 256, 0, stream>>>(
      h, W2, b2, offsets, bucket_tok, bucket_w, out);
}

// Round 2
// 955.279 us; speedup vs baseline: 2.4963x; 2.4963x over previous
//
#include <hip/hip_runtime.h>
#include <hip/hip_bf16.h>
#include <cstdint>
#include <cstddef>

#define T_TOK 4096
#define DM 1024
#define DFF 4096
#define NE 8
#define BT 128                        /* M tile / bucket pad */
#define PADCAP (T_TOK * 2 + NE * BT)  /* 9216 */
#define MTILES (PADCAP / BT)          /* 72 */

typedef __attribute__((ext_vector_type(8))) short short8;
typedef __attribute__((ext_vector_type(4))) float f32x4;

__device__ __forceinline__ unsigned short f2bf(float f) {
  unsigned int u = __float_as_uint(f);
  return (unsigned short)((u + 0x7fff + ((u >> 16) & 1)) >> 16);
}

__device__ __forceinline__ void load_lds16(const void* g, void* l) {
  __builtin_amdgcn_global_load_lds(
      (const __attribute__((address_space(1))) int*)g,
      (__attribute__((address_space(3))) int*)l, 16, 0, 0);
}

// ---------------- gating: one wave per token ----------------
__global__ __launch_bounds__(256) void gate_kernel(
    const float* __restrict__ x, const float* __restrict__ Wg,
    int* __restrict__ counts, int* __restrict__ topk_idx,
    float* __restrict__ topk_w) {
  int gid = blockIdx.x * blockDim.x + threadIdx.x;
  int t = gid >> 6;
  int lane = gid & 63;
  if (t >= T_TOK) return;
  const float* xr = x + (size_t)t * DM;
  float acc[NE];
#pragma unroll
  for (int e = 0; e < NE; ++e) acc[e] = 0.f;
#pragma unroll
  for (int j = 0; j < DM / 64; ++j) {
    int d = lane + j * 64;
    float xv = xr[d];
    const float4* wr = (const float4*)(Wg + (size_t)d * NE);
    float4 w0 = wr[0], w1 = wr[1];
    acc[0] += xv * w0.x; acc[1] += xv * w0.y;
    acc[2] += xv * w0.z; acc[3] += xv * w0.w;
    acc[4] += xv * w1.x; acc[5] += xv * w1.y;
    acc[6] += xv * w1.z; acc[7] += xv * w1.w;
  }
#pragma unroll
  for (int off = 32; off >= 1; off >>= 1) {
#pragma unroll
    for (int e = 0; e < NE; ++e) acc[e] += __shfl_xor(acc[e], off, 64);
  }
  if (lane == 0) {
    int i0 = 0;
#pragma unroll
    for (int e = 1; e < NE; ++e)
      if (acc[e] > acc[i0]) i0 = e;
    int i1 = (i0 == 0) ? 1 : 0;
#pragma unroll
    for (int e = 0; e < NE; ++e)
      if (e != i0 && acc[e] > acc[i1]) i1 = e;
    float e1 = __expf(acc[i1] - acc[i0]);
    float inv = 1.f / (1.f + e1);
    topk_idx[t * 2] = i0;
    topk_idx[t * 2 + 1] = i1;
    topk_w[t * 2] = inv;
    topk_w[t * 2 + 1] = e1 * inv;
    atomicAdd(&counts[i0], 1);
    atomicAdd(&counts[i1], 1);
  }
}

// ---------------- routing bookkeeping ----------------
__global__ void init_kernel(int* counts, int* cursors, int* bucket_tok) {
  int i = blockIdx.x * blockDim.x + threadIdx.x;
  if (i < NE) { counts[i] = 0; cursors[i] = 0; }
  if (i < PADCAP) bucket_tok[i] = -1;
}

__global__ void offsets_kernel(const int* __restrict__ counts,
                               int* __restrict__ offsets) {
  if (threadIdx.x == 0) {
    int o = 0;
    offsets[0] = 0;
    for (int e = 0; e < NE; ++e) {
      o += (counts[e] + BT - 1) & ~(BT - 1);
      offsets[e + 1] = o;
    }
  }
}

__global__ void scatter_kernel(const int* __restrict__ topk_idx,
                               const float* __restrict__ topk_w,
                               const int* __restrict__ offsets,
                               int* __restrict__ cursors,
                               int* __restrict__ bucket_tok,
                               float* __restrict__ bucket_w) {
  int t = blockIdx.x * blockDim.x + threadIdx.x;
  if (t >= T_TOK) return;
#pragma unroll
  for (int k = 0; k < 2; ++k) {
    int e = topk_idx[t * 2 + k];
    float w = topk_w[t * 2 + k];
    int pos = atomicAdd(&cursors[e], 1);
    int slot = offsets[e] + pos;
    bucket_tok[slot] = t;
    bucket_w[slot] = w;
  }
}

// ---------------- x fp32 -> bf16 ----------------
__global__ __launch_bounds__(256) void cvt_x_kernel(
    const float* __restrict__ x, unsigned short* __restrict__ xb) {
  int i = blockIdx.x * 256 + threadIdx.x;  // 4 elems each
  float4 v = ((const float4*)x)[i];
  uint2 o;
  o.x = (unsigned)f2bf(v.x) | ((unsigned)f2bf(v.y) << 16);
  o.y = (unsigned)f2bf(v.z) | ((unsigned)f2bf(v.w) << 16);
  ((uint2*)xb)[i] = o;
}

// ---------------- W [E][K][N] fp32 -> Wt [E][N][K] bf16 ----------------
__global__ __launch_bounds__(256) void transpose_cvt_kernel(
    const float* __restrict__ W, unsigned short* __restrict__ Wt,
    int K, int N) {
  __shared__ float Ls[64][68];
  int e = blockIdx.z;
  const float* We = W + (size_t)e * K * N;
  unsigned short* Wte = Wt + (size_t)e * K * N;
  int k0 = blockIdx.x * 64, n0 = blockIdx.y * 64;
  int tid = threadIdx.x;
  int kr = tid >> 4, nf = (tid & 15) * 4;
#pragma unroll
  for (int p = 0; p < 4; ++p) {
    int k = kr + p * 16;
    float4 v = *(const float4*)(We + (size_t)(k0 + k) * N + n0 + nf);
    Ls[k][nf] = v.x; Ls[k][nf + 1] = v.y;
    Ls[k][nf + 2] = v.z; Ls[k][nf + 3] = v.w;
  }
  __syncthreads();
#pragma unroll
  for (int i = 0; i < 2; ++i) {
    int id = tid + i * 256;
    int n = id >> 3, kc = id & 7;
    short8 hv;
#pragma unroll
    for (int j = 0; j < 8; ++j) hv[j] = (short)f2bf(Ls[kc * 8 + j][n]);
    *(short8*)(Wte + (size_t)(n0 + n) * K + k0 + kc * 8) = hv;
  }
}

// ---------------- MFMA GEMM1: h = relu(gather(xb) @ W1 + b1), bf16 out ----
__global__ __launch_bounds__(256) void gemm1_kernel(
    const unsigned short* __restrict__ xb, const unsigned short* __restrict__ Wt1,
    const float* __restrict__ b1, const int* __restrict__ offsets,
    const int* __restrict__ bucket_tok, unsigned short* __restrict__ h) {
  int r0 = blockIdx.x * BT;
  if (r0 >= offsets[NE]) return;
  int e = 0;
  while (offsets[e + 1] <= r0) ++e;
  int n0 = blockIdx.y * 128;

  // kc-major LDS: slot (kc,row) at byte (kc*128+row)*16 ; 8 bf16 per slot
  __shared__ __align__(16) char As[128 * 64 * 2];
  __shared__ __align__(16) char Bs[128 * 64 * 2];
  __shared__ int toks[BT];

  int tid = threadIdx.x;
  if (tid < BT) toks[tid] = bucket_tok[r0 + tid];
  __syncthreads();

  int lane = tid & 63, w = tid >> 6;
  int wm = w & 1, wn = w >> 1;
  int row = (w & 1) * 64 + lane;  // staging row slot (m for A, n for B)
  int kcb = w >> 1;               // kc parity for this wave
  int tokc = toks[row] < 0 ? 0 : toks[row];
  const unsigned short* gA = xb + (size_t)tokc * DM;
  const unsigned short* gB = Wt1 + ((size_t)e * DFF + n0 + row) * DM;

  f32x4 acc[4][4];
#pragma unroll
  for (int i = 0; i < 4; ++i)
#pragma unroll
    for (int j = 0; j < 4; ++j) acc[i][j] = (f32x4){0.f, 0.f, 0.f, 0.f};

  int g = lane >> 4, l15 = lane & 15;
  for (int k0 = 0; k0 < DM; k0 += 64) {
#pragma unroll
    for (int i = 0; i < 4; ++i) {
      int kc = i * 2 + kcb;
      load_lds16(gA + k0 + kc * 8, As + (kc * 128 + row) * 16);
      load_lds16(gB + k0 + kc * 8, Bs + (kc * 128 + row) * 16);
    }
    __syncthreads();
#pragma unroll
    for (int ks = 0; ks < 2; ++ks) {
      short8 af[4], bfr[4];
      int kb = (ks * 4 + g) * 128;
#pragma unroll
      for (int mi = 0; mi < 4; ++mi)
        af[mi] = *(const short8*)(As + (kb + wm * 64 + mi * 16 + l15) * 16);
#pragma unroll
      for (int nj = 0; nj < 4; ++nj)
        bfr[nj] = *(const short8*)(Bs + (kb + wn * 64 + nj * 16 + l15) * 16);
#pragma unroll
      for (int mi = 0; mi < 4; ++mi)
#pragma unroll
        for (int nj = 0; nj < 4; ++nj)
          acc[mi][nj] = __builtin_amdgcn_mfma_f32_16x16x32_bf16(
              af[mi], bfr[nj], acc[mi][nj], 0, 0, 0);
    }
    __syncthreads();
  }

  const float* b1e = b1 + (size_t)e * DFF;
#pragma unroll
  for (int nj = 0; nj < 4; ++nj) {
    int n = n0 + wn * 64 + nj * 16 + l15;
    float bv = b1e[n];
#pragma unroll
    for (int mi = 0; mi < 4; ++mi) {
      int mb = r0 + wm * 64 + mi * 16 + g * 4;
#pragma unroll
      for (int r = 0; r < 4; ++r) {
        float v = acc[mi][nj][r] + bv;
        h[(size_t)(mb + r) * DFF + n] = f2bf(fmaxf(v, 0.f));
      }
    }
  }
}

// ---------------- MFMA GEMM2: out += w * (h @ W2 + b2) ----------------
__global__ __launch_bounds__(256) void gemm2_kernel(
    const unsigned short* __restrict__ h, const unsigned short* __restrict__ Wt2,
    const float* __restrict__ b2, const int* __restrict__ offsets,
    const int* __restrict__ bucket_tok, const float* __restrict__ bucket_w,
    float* __restrict__ out) {
  int r0 = blockIdx.x * BT;
  if (r0 >= offsets[NE]) return;
  int e = 0;
  while (offsets[e + 1] <= r0) ++e;
  int n0 = blockIdx.y * 128;

  __shared__ __align__(16) char As[128 * 64 * 2];
  __shared__ __align__(16) char Bs[128 * 64 * 2];
  __shared__ int toks[BT];
  __shared__ float wts[BT];

  int tid = threadIdx.x;
  if (tid < BT) {
    toks[tid] = bucket_tok[r0 + tid];
    wts[tid] = bucket_w[r0 + tid];
  }
  __syncthreads();

  int lane = tid & 63, w = tid >> 6;
  int wm = w & 1, wn = w >> 1;
  int row = (w & 1) * 64 + lane;
  int kcb = w >> 1;
  const unsigned short* gA = h + (size_t)(r0 + row) * DFF;
  const unsigned short* gB = Wt2 + ((size_t)e * DM + n0 + row) * DFF;

  f32x4 acc[4][4];
#pragma unroll
  for (int i = 0; i < 4; ++i)
#pragma unroll
    for (int j = 0; j < 4; ++j) acc[i][j] = (f32x4){0.f, 0.f, 0.f, 0.f};

  int g = lane >> 4, l15 = lane & 15;
  for (int k0 = 0; k0 < DFF; k0 += 64) {
#pragma unroll
    for (int i = 0; i < 4; ++i) {
      int kc = i * 2 + kcb;
      load_lds16(gA + k0 + kc * 8, As + (kc * 128 + row) * 16);
      load_lds16(gB + k0 + kc * 8, Bs + (kc * 128 + row) * 16);
    }
    __syncthreads();
#pragma unroll
    for (int ks = 0; ks < 2; ++ks) {
      short8 af[4], bfr[4];
      int kb = (ks * 4 + g) * 128;
#pragma unroll
      for (int mi = 0; mi < 4; ++mi)
        af[mi] = *(const short8*)(As + (kb + wm * 64 + mi * 16 + l15) * 16);
#pragma unroll
      for (int nj = 0; nj < 4; ++nj)
        bfr[nj] = *(const short8*)(Bs + (kb + wn * 64 + nj * 16 + l15) * 16);
#pragma unroll
      for (int mi = 0; mi < 4; ++mi)
#pragma unroll
        for (int nj = 0; nj < 4; ++nj)
          acc[mi][nj] = __builtin_amdgcn_mfma_f32_16x16x32_bf16(
              af[mi], bfr[nj], acc[mi][nj], 0, 0, 0);
    }
    __syncthreads();
  }

  const float* b2e = b2 + (size_t)e * DM;
#pragma unroll
  for (int nj = 0; nj < 4; ++nj) {
    int n = n0 + wn * 64 + nj * 16 + l15;
    float bv = b2e[n];
#pragma unroll
    for (int mi = 0; mi < 4; ++mi) {
      int mb = wm * 64 + mi * 16 + g * 4;
#pragma unroll
      for (int r = 0; r < 4; ++r) {
        int m = mb + r;
        int tk = toks[m];
        if (tk < 0) continue;
        atomicAdd(&out[(size_t)tk * DM + n],
                  (acc[mi][nj][r] + bv) * wts[m]);
      }
    }
  }
}

extern "C" void kernel_launch(void* const* d_in, const int* in_sizes, int n_in,
                              void* d_out, int out_size, void* d_ws,
                              size_t ws_size, hipStream_t stream) {
  const float* x = (const float*)d_in[0];
  const float* Wg = (const float*)d_in[1];
  const float* W1 = (const float*)d_in[2];
  const float* b1 = (const float*)d_in[3];
  const float* W2 = (const float*)d_in[4];
  const float* b2 = (const float*)d_in[5];
  float* out = (float*)d_out;

  // ---- workspace layout ----
  // [0, 1MB): int bookkeeping; 1MB: xb (8MB); 9MB: Wt (64MB, aliased W1/W2);
  // 73MB+: h bf16 (72MB). Total ~145MB.
  int* ws_i = (int*)d_ws;
  int* counts = ws_i;
  int* offsets = ws_i + 8;
  int* cursors = ws_i + 20;
  int* bucket_tok = ws_i + 32;
  float* bucket_w = (float*)(ws_i + 32 + PADCAP);
  int* topk_idx = ws_i + 32 + 2 * PADCAP;
  float* topk_w = (float*)(ws_i + 32 + 2 * PADCAP + 2 * T_TOK);

  const size_t XB_OFF = 1u << 20;
  const size_t WT_OFF = XB_OFF + (size_t)T_TOK * DM * 2;
  const size_t H_OFF = WT_OFF + (size_t)NE * DM * DFF * 2;
  unsigned short* xb = (unsigned short*)((char*)d_ws + XB_OFF);
  unsigned short* Wt = (unsigned short*)((char*)d_ws + WT_OFF);
  unsigned short* h = (unsigned short*)((char*)d_ws + H_OFF);

  hipMemsetAsync(d_out, 0, (size_t)T_TOK * DM * sizeof(float), stream);
  init_kernel<<<(PADCAP + 255) / 256, 256, 0, stream>>>(counts, cursors,
                                                        bucket_tok);
  cvt_x_kernel<<<(T_TOK * DM / 4) / 256, 256, 0, stream>>>(x, xb);
  // transpose W1 -> Wt  (K=DM rows, N=DFF cols)
  transpose_cvt_kernel<<<dim3(DM / 64, DFF / 64, NE), 256, 0, stream>>>(
      W1, Wt, DM, DFF);
  gate_kernel<<<T_TOK / 4, 256, 0, stream>>>(x, Wg, counts, topk_idx, topk_w);
  offsets_kernel<<<1, 64, 0, stream>>>(counts, offsets);
  scatter_kernel<<<T_TOK / 256, 256, 0, stream>>>(topk_idx, topk_w, offsets,
                                                  cursors, bucket_tok, bucket_w);
  gemm1_kernel<<<dim3(MTILES, DFF / 128), 256, 0, stream>>>(
      xb, Wt, b1, offsets, bucket_tok, h);
  // transpose W2 -> Wt (aliased; stream-ordered after gemm1)
  transpose_cvt_kernel<<<dim3(DFF / 64, DM / 64, NE), 256, 0, stream>>>(
      W2, Wt, DFF, DM);
  gemm2_kernel<<<dim3(MTILES, DM / 128), 256, 0, stream>>>(
      h, Wt, b2, offsets, bucket_tok, bucket_w, out);
}

// Round 3
// 742.803 us; speedup vs baseline: 3.2103x; 1.2860x over previous
//
#include <hip/hip_runtime.h>
#include <hip/hip_bf16.h>
#include <cstdint>
#include <cstddef>

#define T_TOK 4096
#define DM 1024
#define DFF 4096
#define NE 8
#define BT 128                        /* M tile / bucket pad */
#define BK 64
#define PADCAP (T_TOK * 2 + NE * BT)  /* 9216 */
#define MTILES (PADCAP / BT)          /* 72 */

typedef __attribute__((ext_vector_type(8))) short short8;
typedef __attribute__((ext_vector_type(4))) float f32x4;

__device__ __forceinline__ unsigned short f2bf(float f) {
  unsigned int u = __float_as_uint(f);
  return (unsigned short)((u + 0x7fff + ((u >> 16) & 1)) >> 16);
}

__device__ __forceinline__ void load_lds16(const void* g, void* l) {
  __builtin_amdgcn_global_load_lds(
      (const __attribute__((address_space(1))) int*)g,
      (__attribute__((address_space(3))) int*)l, 16, 0, 0);
}

// ---------------- gating + x->bf16: one wave per token ----------------
__global__ __launch_bounds__(256) void gate_kernel(
    const float* __restrict__ x, const float* __restrict__ Wg,
    int* __restrict__ counts, int* __restrict__ topk_idx,
    float* __restrict__ topk_w, unsigned short* __restrict__ xb) {
  int gid = blockIdx.x * blockDim.x + threadIdx.x;
  int t = gid >> 6;
  int lane = gid & 63;
  if (t >= T_TOK) return;
  const float* xr = x + (size_t)t * DM;
  unsigned short* xbr = xb + (size_t)t * DM;
  float acc[NE];
#pragma unroll
  for (int e = 0; e < NE; ++e) acc[e] = 0.f;
#pragma unroll
  for (int j = 0; j < DM / 64; ++j) {
    int d = lane + j * 64;
    float xv = xr[d];
    xbr[d] = f2bf(xv);  // fused bf16 conversion (128B contiguous per instr)
    const float4* wr = (const float4*)(Wg + (size_t)d * NE);
    float4 w0 = wr[0], w1 = wr[1];
    acc[0] += xv * w0.x; acc[1] += xv * w0.y;
    acc[2] += xv * w0.z; acc[3] += xv * w0.w;
    acc[4] += xv * w1.x; acc[5] += xv * w1.y;
    acc[6] += xv * w1.z; acc[7] += xv * w1.w;
  }
#pragma unroll
  for (int off = 32; off >= 1; off >>= 1) {
#pragma unroll
    for (int e = 0; e < NE; ++e) acc[e] += __shfl_xor(acc[e], off, 64);
  }
  if (lane == 0) {
    int i0 = 0;
#pragma unroll
    for (int e = 1; e < NE; ++e)
      if (acc[e] > acc[i0]) i0 = e;
    int i1 = (i0 == 0) ? 1 : 0;
#pragma unroll
    for (int e = 0; e < NE; ++e)
      if (e != i0 && acc[e] > acc[i1]) i1 = e;
    float e1 = __expf(acc[i1] - acc[i0]);
    float inv = 1.f / (1.f + e1);
    topk_idx[t * 2] = i0;
    topk_idx[t * 2 + 1] = i1;
    topk_w[t * 2] = inv;
    topk_w[t * 2 + 1] = e1 * inv;
    atomicAdd(&counts[i0], 1);
    atomicAdd(&counts[i1], 1);
  }
}

// ---------------- routing bookkeeping ----------------
__global__ void init_kernel(int* counts, int* cursors, int* bucket_tok) {
  int i = blockIdx.x * blockDim.x + threadIdx.x;
  if (i < NE) { counts[i] = 0; cursors[i] = 0; }
  if (i < PADCAP) bucket_tok[i] = -1;
}

__global__ void offsets_kernel(const int* __restrict__ counts,
                               int* __restrict__ offsets) {
  if (threadIdx.x == 0) {
    int o = 0;
    offsets[0] = 0;
    for (int e = 0; e < NE; ++e) {
      o += (counts[e] + BT - 1) & ~(BT - 1);
      offsets[e + 1] = o;
    }
  }
}

__global__ void scatter_kernel(const int* __restrict__ topk_idx,
                               const float* __restrict__ topk_w,
                               const int* __restrict__ offsets,
                               int* __restrict__ cursors,
                               int* __restrict__ bucket_tok,
                               float* __restrict__ bucket_w) {
  int t = blockIdx.x * blockDim.x + threadIdx.x;
  if (t >= T_TOK) return;
#pragma unroll
  for (int k = 0; k < 2; ++k) {
    int e = topk_idx[t * 2 + k];
    float w = topk_w[t * 2 + k];
    int pos = atomicAdd(&cursors[e], 1);
    int slot = offsets[e] + pos;
    bucket_tok[slot] = t;
    bucket_w[slot] = w;
  }
}

// ---------------- W [E][K][N] fp32 -> Wt [E][N][K] bf16 ----------------
__global__ __launch_bounds__(256) void transpose_cvt_kernel(
    const float* __restrict__ W, unsigned short* __restrict__ Wt,
    int K, int N) {
  __shared__ float Ls[64][68];
  int e = blockIdx.z;
  const float* We = W + (size_t)e * K * N;
  unsigned short* Wte = Wt + (size_t)e * K * N;
  int k0 = blockIdx.x * 64, n0 = blockIdx.y * 64;
  int tid = threadIdx.x;
  int kr = tid >> 4, nf = (tid & 15) * 4;
#pragma unroll
  for (int p = 0; p < 4; ++p) {
    int k = kr + p * 16;
    float4 v = *(const float4*)(We + (size_t)(k0 + k) * N + n0 + nf);
    Ls[k][nf] = v.x; Ls[k][nf + 1] = v.y;
    Ls[k][nf + 2] = v.z; Ls[k][nf + 3] = v.w;
  }
  __syncthreads();
#pragma unroll
  for (int i = 0; i < 2; ++i) {
    int id = tid + i * 256;
    int n = id >> 3, kc = id & 7;
    short8 hv;
#pragma unroll
    for (int j = 0; j < 8; ++j) hv[j] = (short)f2bf(Ls[kc * 8 + j][n]);
    *(short8*)(Wte + (size_t)(n0 + n) * K + k0 + kc * 8) = hv;
  }
}

// LDS tiles: row-major [128 rows][64 k] bf16 (128 B/row). The 16-B k-chunk
// slot s of row m holds global chunk s^(m&7) (XOR swizzle applied on the
// GLOBAL read side so global_load_lds stays lane-contiguous AND frag
// ds_read_b128 is only 2-way bank-aliased = free).

// ---------------- MFMA GEMM1: h = relu(gather(xb) @ W1 + b1) ----------
__global__ __launch_bounds__(256) void gemm1_kernel(
    const unsigned short* __restrict__ xb, const unsigned short* __restrict__ Wt1,
    const float* __restrict__ b1, const int* __restrict__ offsets,
    const int* __restrict__ bucket_tok, unsigned short* __restrict__ h) {
  int r0 = blockIdx.x * BT;
  if (r0 >= offsets[NE]) return;
  int e = 0;
  while (offsets[e + 1] <= r0) ++e;
  int n0 = blockIdx.y * 128;

  __shared__ __align__(16) short As[128 * 64];
  __shared__ __align__(16) short Bs[128 * 64];
  __shared__ int toks[BT];

  int tid = threadIdx.x;
  if (tid < BT) toks[tid] = bucket_tok[r0 + tid];
  __syncthreads();

  int lane = tid & 63, w = tid >> 6;
  int rsub = lane >> 3, kc = lane & 7;
  int jsw = (kc ^ rsub) * 8;  // swizzled global chunk (elements)
  const unsigned short* aptr[4];
  const unsigned short* bptr[4];
#pragma unroll
  for (int i = 0; i < 4; ++i) {
    int m = w * 32 + i * 8 + rsub;
    int tk = toks[m]; if (tk < 0) tk = 0;
    aptr[i] = xb + (size_t)tk * DM + jsw;
    bptr[i] = Wt1 + ((size_t)e * DFF + n0 + m) * DM + jsw;
  }
  int ldsA = w * 2048 + lane * 8;  // element offset; inst i adds i*512

  int wm = w & 1, wn = w >> 1;
  int g = lane >> 4, l15 = lane & 15;
  int x7 = l15 & 7;
  int csel0 = ((g) ^ x7) * 8;
  int csel1 = ((4 + g) ^ x7) * 8;

  f32x4 acc[4][4];
#pragma unroll
  for (int i = 0; i < 4; ++i)
#pragma unroll
    for (int jj = 0; jj < 4; ++jj) acc[i][jj] = (f32x4){0.f, 0.f, 0.f, 0.f};

  for (int k0 = 0; k0 < DM; k0 += BK) {
#pragma unroll
    for (int i = 0; i < 4; ++i) {
      load_lds16(aptr[i] + k0, &As[ldsA + i * 512]);
      load_lds16(bptr[i] + k0, &Bs[ldsA + i * 512]);
    }
    __syncthreads();
#pragma unroll
    for (int ks = 0; ks < 2; ++ks) {
      int cs = ks ? csel1 : csel0;
      short8 af[4], bfr[4];
#pragma unroll
      for (int mi = 0; mi < 4; ++mi)
        af[mi] = *(const short8*)&As[(wm * 64 + mi * 16 + l15) * 64 + cs];
#pragma unroll
      for (int nj = 0; nj < 4; ++nj)
        bfr[nj] = *(const short8*)&Bs[(wn * 64 + nj * 16 + l15) * 64 + cs];
#pragma unroll
      for (int mi = 0; mi < 4; ++mi)
#pragma unroll
        for (int nj = 0; nj < 4; ++nj)
          acc[mi][nj] = __builtin_amdgcn_mfma_f32_16x16x32_bf16(
              af[mi], bfr[nj], acc[mi][nj], 0, 0, 0);
    }
    __syncthreads();
  }

  const float* b1e = b1 + (size_t)e * DFF;
#pragma unroll
  for (int nj = 0; nj < 4; ++nj) {
    int n = n0 + wn * 64 + nj * 16 + l15;
    float bv = b1e[n];
#pragma unroll
    for (int mi = 0; mi < 4; ++mi) {
      int mb = r0 + wm * 64 + mi * 16 + g * 4;
#pragma unroll
      for (int r = 0; r < 4; ++r) {
        float v = acc[mi][nj][r] + bv;
        h[(size_t)(mb + r) * DFF + n] = f2bf(fmaxf(v, 0.f));
      }
    }
  }
}

// ---------------- MFMA GEMM2: out += w * (h @ W2 + b2), split-K x2 ------
__global__ __launch_bounds__(256) void gemm2_kernel(
    const unsigned short* __restrict__ h, const unsigned short* __restrict__ Wt2,
    const float* __restrict__ b2, const int* __restrict__ offsets,
    const int* __restrict__ bucket_tok, const float* __restrict__ bucket_w,
    float* __restrict__ out) {
  int r0 = blockIdx.x * BT;
  if (r0 >= offsets[NE]) return;
  int e = 0;
  while (offsets[e + 1] <= r0) ++e;
  int n0 = blockIdx.y * 128;
  int kbeg = blockIdx.z * (DFF / 2);

  __shared__ __align__(16) short As[128 * 64];
  __shared__ __align__(16) short Bs[128 * 64];
  __shared__ int toks[BT];
  __shared__ float wts[BT];

  int tid = threadIdx.x;
  if (tid < BT) {
    toks[tid] = bucket_tok[r0 + tid];
    wts[tid] = bucket_w[r0 + tid];
  }
  __syncthreads();

  int lane = tid & 63, w = tid >> 6;
  int rsub = lane >> 3, kc = lane & 7;
  int jsw = (kc ^ rsub) * 8;
  const unsigned short* aptr[4];
  const unsigned short* bptr[4];
#pragma unroll
  for (int i = 0; i < 4; ++i) {
    int m = w * 32 + i * 8 + rsub;
    aptr[i] = h + ((size_t)(r0 + m)) * DFF + jsw;
    bptr[i] = Wt2 + ((size_t)e * DM + n0 + m) * DFF + jsw;
  }
  int ldsA = w * 2048 + lane * 8;

  int wm = w & 1, wn = w >> 1;
  int g = lane >> 4, l15 = lane & 15;
  int x7 = l15 & 7;
  int csel0 = ((g) ^ x7) * 8;
  int csel1 = ((4 + g) ^ x7) * 8;

  f32x4 acc[4][4];
#pragma unroll
  for (int i = 0; i < 4; ++i)
#pragma unroll
    for (int jj = 0; jj < 4; ++jj) acc[i][jj] = (f32x4){0.f, 0.f, 0.f, 0.f};

  for (int k0 = kbeg; k0 < kbeg + DFF / 2; k0 += BK) {
#pragma unroll
    for (int i = 0; i < 4; ++i) {
      load_lds16(aptr[i] + k0, &As[ldsA + i * 512]);
      load_lds16(bptr[i] + k0, &Bs[ldsA + i * 512]);
    }
    __syncthreads();
#pragma unroll
    for (int ks = 0; ks < 2; ++ks) {
      int cs = ks ? csel1 : csel0;
      short8 af[4], bfr[4];
#pragma unroll
      for (int mi = 0; mi < 4; ++mi)
        af[mi] = *(const short8*)&As[(wm * 64 + mi * 16 + l15) * 64 + cs];
#pragma unroll
      for (int nj = 0; nj < 4; ++nj)
        bfr[nj] = *(const short8*)&Bs[(wn * 64 + nj * 16 + l15) * 64 + cs];
#pragma unroll
      for (int mi = 0; mi < 4; ++mi)
#pragma unroll
        for (int nj = 0; nj < 4; ++nj)
          acc[mi][nj] = __builtin_amdgcn_mfma_f32_16x16x32_bf16(
              af[mi], bfr[nj], acc[mi][nj], 0, 0, 0);
    }
    __syncthreads();
  }

  const float* b2e = b2 + (size_t)e * DM;
  float bscale = (blockIdx.z == 0) ? 1.f : 0.f;
#pragma unroll
  for (int nj = 0; nj < 4; ++nj) {
    int n = n0 + wn * 64 + nj * 16 + l15;
    float bv = b2e[n] * bscale;
#pragma unroll
    for (int mi = 0; mi < 4; ++mi) {
      int mb = wm * 64 + mi * 16 + g * 4;
#pragma unroll
      for (int r = 0; r < 4; ++r) {
        int m = mb + r;
        int tk = toks[m];
        if (tk < 0) continue;
        atomicAdd(&out[(size_t)tk * DM + n],
                  (acc[mi][nj][r] + bv) * wts[m]);
      }
    }
  }
}

extern "C" void kernel_launch(void* const* d_in, const int* in_sizes, int n_in,
                              void* d_out, int out_size, void* d_ws,
                              size_t ws_size, hipStream_t stream) {
  const float* x = (const float*)d_in[0];
  const float* Wg = (const float*)d_in[1];
  const float* W1 = (const float*)d_in[2];
  const float* b1 = (const float*)d_in[3];
  const float* W2 = (const float*)d_in[4];
  const float* b2 = (const float*)d_in[5];
  float* out = (float*)d_out;

  int* ws_i = (int*)d_ws;
  int* counts = ws_i;
  int* offsets = ws_i + 8;
  int* cursors = ws_i + 20;
  int* bucket_tok = ws_i + 32;
  float* bucket_w = (float*)(ws_i + 32 + PADCAP);
  int* topk_idx = ws_i + 32 + 2 * PADCAP;
  float* topk_w = (float*)(ws_i + 32 + 2 * PADCAP + 2 * T_TOK);

  const size_t XB_OFF = 1u << 20;
  const size_t WT_OFF = XB_OFF + (size_t)T_TOK * DM * 2;
  const size_t H_OFF = WT_OFF + (size_t)NE * DM * DFF * 2;
  unsigned short* xb = (unsigned short*)((char*)d_ws + XB_OFF);
  unsigned short* Wt = (unsigned short*)((char*)d_ws + WT_OFF);
  unsigned short* h = (unsigned short*)((char*)d_ws + H_OFF);

  hipMemsetAsync(d_out, 0, (size_t)T_TOK * DM * sizeof(float), stream);
  init_kernel<<<(PADCAP + 255) / 256, 256, 0, stream>>>(counts, cursors,
                                                        bucket_tok);
  gate_kernel<<<T_TOK / 4, 256, 0, stream>>>(x, Wg, counts, topk_idx, topk_w,
                                             xb);
  offsets_kernel<<<1, 64, 0, stream>>>(counts, offsets);
  scatter_kernel<<<T_TOK / 256, 256, 0, stream>>>(topk_idx, topk_w, offsets,
                                                  cursors, bucket_tok, bucket_w);
  transpose_cvt_kernel<<<dim3(DM / 64, DFF / 64, NE), 256, 0, stream>>>(
      W1, Wt, DM, DFF);
  gemm1_kernel<<<dim3(MTILES, DFF / 128), 256, 0, stream>>>(
      xb, Wt, b1, offsets, bucket_tok, h);
  transpose_cvt_kernel<<<dim3(DFF / 64, DM / 64, NE), 256, 0, stream>>>(
      W2, Wt, DFF, DM);
  gemm2_kernel<<<dim3(MTILES, DM / 128, 2), 256, 0, stream>>>(
      h, Wt, b2, offsets, bucket_tok, bucket_w, out);
}

// Round 4
// 710.876 us; speedup vs baseline: 3.3545x; 1.0449x over previous
//
#include <hip/hip_runtime.h>
#include <hip/hip_bf16.h>
#include <cstdint>
#include <cstddef>

#define T_TOK 4096
#define DM 1024
#define DFF 4096
#define NE 8
#define BT 128                        /* M tile / bucket pad */
#define BK 64
#define PADCAP (T_TOK * 2 + NE * BT)  /* 9216 */
#define MTILES (PADCAP / BT)          /* 72 */

typedef __attribute__((ext_vector_type(8))) short short8;
typedef __attribute__((ext_vector_type(4))) float f32x4;

__device__ __forceinline__ unsigned short f2bf(float f) {
  unsigned int u = __float_as_uint(f);
  return (unsigned short)((u + 0x7fff + ((u >> 16) & 1)) >> 16);
}
__device__ __forceinline__ float bf2f(unsigned short u) {
  return __uint_as_float((unsigned int)u << 16);
}

__device__ __forceinline__ void load_lds16(const void* g, void* l) {
  __builtin_amdgcn_global_load_lds(
      (const __attribute__((address_space(1))) int*)g,
      (__attribute__((address_space(3))) int*)l, 16, 0, 0);
}

// waitcnt imm (gfx9): vmcnt[3:0]|exp[6:4]|lgkm[11:8]|vmcnt_hi[15:14]
#define WAIT_VM8() __builtin_amdgcn_s_waitcnt(0x0F78) /* vmcnt(8), lgkm/exp free */
#define WAIT_VM0() __builtin_amdgcn_s_waitcnt(0x0F70) /* vmcnt(0) */
#define BARRIER()                          \
  do {                                     \
    __asm__ volatile("" ::: "memory");     \
    __builtin_amdgcn_s_barrier();          \
    __asm__ volatile("" ::: "memory");     \
  } while (0)

// ---------------- gating + x->bf16: one wave per token ----------------
__global__ __launch_bounds__(256) void gate_kernel(
    const float* __restrict__ x, const float* __restrict__ Wg,
    int* __restrict__ counts, int* __restrict__ topk_idx,
    float* __restrict__ topk_w, unsigned short* __restrict__ xb) {
  int gid = blockIdx.x * blockDim.x + threadIdx.x;
  int t = gid >> 6;
  int lane = gid & 63;
  if (t >= T_TOK) return;
  const float* xr = x + (size_t)t * DM;
  unsigned short* xbr = xb + (size_t)t * DM;
  float acc[NE];
#pragma unroll
  for (int e = 0; e < NE; ++e) acc[e] = 0.f;
#pragma unroll
  for (int j = 0; j < DM / 64; ++j) {
    int d = lane + j * 64;
    float xv = xr[d];
    xbr[d] = f2bf(xv);
    const float4* wr = (const float4*)(Wg + (size_t)d * NE);
    float4 w0 = wr[0], w1 = wr[1];
    acc[0] += xv * w0.x; acc[1] += xv * w0.y;
    acc[2] += xv * w0.z; acc[3] += xv * w0.w;
    acc[4] += xv * w1.x; acc[5] += xv * w1.y;
    acc[6] += xv * w1.z; acc[7] += xv * w1.w;
  }
#pragma unroll
  for (int off = 32; off >= 1; off >>= 1) {
#pragma unroll
    for (int e = 0; e < NE; ++e) acc[e] += __shfl_xor(acc[e], off, 64);
  }
  if (lane == 0) {
    int i0 = 0;
#pragma unroll
    for (int e = 1; e < NE; ++e)
      if (acc[e] > acc[i0]) i0 = e;
    int i1 = (i0 == 0) ? 1 : 0;
#pragma unroll
    for (int e = 0; e < NE; ++e)
      if (e != i0 && acc[e] > acc[i1]) i1 = e;
    float e1 = __expf(acc[i1] - acc[i0]);
    float inv = 1.f / (1.f + e1);
    topk_idx[t * 2] = i0;
    topk_idx[t * 2 + 1] = i1;
    topk_w[t * 2] = inv;
    topk_w[t * 2 + 1] = e1 * inv;
    atomicAdd(&counts[i0], 1);
    atomicAdd(&counts[i1], 1);
  }
}

// ---------------- routing bookkeeping ----------------
__global__ void init_kernel(int* counts, int* cursors, int* bucket_tok) {
  int i = blockIdx.x * blockDim.x + threadIdx.x;
  if (i < NE) { counts[i] = 0; cursors[i] = 0; }
  if (i < PADCAP) bucket_tok[i] = -1;
}

__global__ void offsets_kernel(const int* __restrict__ counts,
                               int* __restrict__ offsets) {
  if (threadIdx.x == 0) {
    int o = 0;
    offsets[0] = 0;
    for (int e = 0; e < NE; ++e) {
      o += (counts[e] + BT - 1) & ~(BT - 1);
      offsets[e + 1] = o;
    }
  }
}

__global__ void scatter_kernel(const int* __restrict__ topk_idx,
                               const int* __restrict__ offsets,
                               int* __restrict__ cursors,
                               int* __restrict__ bucket_tok,
                               int* __restrict__ slot_of) {
  int t = blockIdx.x * blockDim.x + threadIdx.x;
  if (t >= T_TOK) return;
#pragma unroll
  for (int k = 0; k < 2; ++k) {
    int e = topk_idx[t * 2 + k];
    int pos = atomicAdd(&cursors[e], 1);
    int slot = offsets[e] + pos;
    bucket_tok[slot] = t;
    slot_of[t * 2 + k] = slot;
  }
}

// ---------------- W [E][K][N] fp32 -> Wt [E][N][K] bf16 ----------------
__global__ __launch_bounds__(256) void transpose_cvt_kernel(
    const float* __restrict__ W, unsigned short* __restrict__ Wt,
    int K, int N) {
  __shared__ float Ls[64][68];
  int e = blockIdx.z;
  const float* We = W + (size_t)e * K * N;
  unsigned short* Wte = Wt + (size_t)e * K * N;
  int k0 = blockIdx.x * 64, n0 = blockIdx.y * 64;
  int tid = threadIdx.x;
  int kr = tid >> 4, nf = (tid & 15) * 4;
#pragma unroll
  for (int p = 0; p < 4; ++p) {
    int k = kr + p * 16;
    float4 v = *(const float4*)(We + (size_t)(k0 + k) * N + n0 + nf);
    Ls[k][nf] = v.x; Ls[k][nf + 1] = v.y;
    Ls[k][nf + 2] = v.z; Ls[k][nf + 3] = v.w;
  }
  __syncthreads();
#pragma unroll
  for (int i = 0; i < 2; ++i) {
    int id = tid + i * 256;
    int n = id >> 3, kc = id & 7;
    short8 hv;
#pragma unroll
    for (int j = 0; j < 8; ++j) hv[j] = (short)f2bf(Ls[kc * 8 + j][n]);
    *(short8*)(Wte + (size_t)(n0 + n) * K + k0 + kc * 8) = hv;
  }
}

// LDS tiles: double-buffered row-major [128 rows][64 k] bf16. 16-B k-chunk
// slot s of row m holds global chunk s^(m&7) (XOR swizzle on the global
// side: global_load_lds stays lane-contiguous, frag ds_read_b128 is
// conflict-free at the 8-cyc floor — verified SQ_LDS_BANK_CONFLICT=0 in R2).
// K-loop: issue next tile's 8 global_load_lds, wait vmcnt(8) (current tile
// done, next stays in flight), raw s_barrier, compute, s_barrier.

// ---------------- MFMA GEMM1: h = relu(gather(xb) @ W1 + b1) ----------
__global__ __launch_bounds__(256) void gemm1_kernel(
    const unsigned short* __restrict__ xb, const unsigned short* __restrict__ Wt1,
    const float* __restrict__ b1, const int* __restrict__ offsets,
    const int* __restrict__ bucket_tok, unsigned short* __restrict__ h) {
  int r0 = blockIdx.x * BT;
  if (r0 >= offsets[NE]) return;
  int e = 0;
  while (offsets[e + 1] <= r0) ++e;
  int n0 = blockIdx.y * 128;

  __shared__ __align__(16) short As[2 * 128 * 64];
  __shared__ __align__(16) short Bs[2 * 128 * 64];
  __shared__ int toks[BT];

  int tid = threadIdx.x;
  if (tid < BT) toks[tid] = bucket_tok[r0 + tid];
  __syncthreads();

  int lane = tid & 63, w = tid >> 6;
  int rsub = lane >> 3, kc = lane & 7;
  int jsw = (kc ^ rsub) * 8;
  const unsigned short* ga[4];
  const unsigned short* gb[4];
#pragma unroll
  for (int i = 0; i < 4; ++i) {
    int m = w * 32 + i * 8 + rsub;
    int tk = toks[m]; if (tk < 0) tk = 0;
    ga[i] = xb + (size_t)tk * DM + jsw;
    gb[i] = Wt1 + ((size_t)e * DFF + n0 + m) * DM + jsw;
  }
  int ldsW = w * 2048 + lane * 8;

  int wm = w & 1, wn = w >> 1;
  int g = lane >> 4, l15 = lane & 15;
  int x7 = l15 & 7;
  int csel0 = (g ^ x7) * 8;
  int csel1 = ((4 + g) ^ x7) * 8;

  f32x4 acc[4][4];
#pragma unroll
  for (int i = 0; i < 4; ++i)
#pragma unroll
    for (int jj = 0; jj < 4; ++jj) acc[i][jj] = (f32x4){0.f, 0.f, 0.f, 0.f};

  // prologue: tile 0 into buf 0
#pragma unroll
  for (int i = 0; i < 4; ++i) {
    load_lds16(ga[i], &As[ldsW + i * 512]);
    load_lds16(gb[i], &Bs[ldsW + i * 512]);
  }

  int buf = 0;
  const int NIT = DM / BK;  // 16
  for (int it = 0; it < NIT; ++it) {
    if (it + 1 < NIT) {
      int ko = (it + 1) * BK;
      int dst = (buf ^ 1) * 8192 + ldsW;
#pragma unroll
      for (int i = 0; i < 4; ++i) {
        load_lds16(ga[i] + ko, &As[dst + i * 512]);
        load_lds16(gb[i] + ko, &Bs[dst + i * 512]);
      }
      WAIT_VM8();
    } else {
      WAIT_VM0();
    }
    BARRIER();
    int bb = buf * 8192;
#pragma unroll
    for (int ks = 0; ks < 2; ++ks) {
      int cs = ks ? csel1 : csel0;
      short8 af[4], bfr[4];
#pragma unroll
      for (int mi = 0; mi < 4; ++mi)
        af[mi] = *(const short8*)&As[bb + (wm * 64 + mi * 16 + l15) * 64 + cs];
#pragma unroll
      for (int nj = 0; nj < 4; ++nj)
        bfr[nj] = *(const short8*)&Bs[bb + (wn * 64 + nj * 16 + l15) * 64 + cs];
#pragma unroll
      for (int mi = 0; mi < 4; ++mi)
#pragma unroll
        for (int nj = 0; nj < 4; ++nj)
          acc[mi][nj] = __builtin_amdgcn_mfma_f32_16x16x32_bf16(
              af[mi], bfr[nj], acc[mi][nj], 0, 0, 0);
    }
    BARRIER();
    buf ^= 1;
  }

  const float* b1e = b1 + (size_t)e * DFF;
#pragma unroll
  for (int nj = 0; nj < 4; ++nj) {
    int n = n0 + wn * 64 + nj * 16 + l15;
    float bv = b1e[n];
#pragma unroll
    for (int mi = 0; mi < 4; ++mi) {
      int mb = r0 + wm * 64 + mi * 16 + g * 4;
#pragma unroll
      for (int r = 0; r < 4; ++r) {
        float v = acc[mi][nj][r] + bv;
        h[(size_t)(mb + r) * DFF + n] = f2bf(fmaxf(v, 0.f));
      }
    }
  }
}

// ------- MFMA GEMM2: S[z][slot] = (h @ W2)(k-split z) + (z==0)*b2, bf16 ---
__global__ __launch_bounds__(256) void gemm2_kernel(
    const unsigned short* __restrict__ h, const unsigned short* __restrict__ Wt2,
    const float* __restrict__ b2, const int* __restrict__ offsets,
    unsigned short* __restrict__ S) {
  // x: 16 = (n0 0..7, z 0..1) variants of one M-tile (A-reuse grouping)
  int r0 = blockIdx.y * BT;
  if (r0 >= offsets[NE]) return;
  int e = 0;
  while (offsets[e + 1] <= r0) ++e;
  int n0 = (blockIdx.x & 7) * 128;
  int z = blockIdx.x >> 3;
  int kbeg = z * (DFF / 2);

  __shared__ __align__(16) short As[2 * 128 * 64];
  __shared__ __align__(16) short Bs[2 * 128 * 64];

  int tid = threadIdx.x;
  int lane = tid & 63, w = tid >> 6;
  int rsub = lane >> 3, kc = lane & 7;
  int jsw = (kc ^ rsub) * 8;
  const unsigned short* ga[4];
  const unsigned short* gb[4];
#pragma unroll
  for (int i = 0; i < 4; ++i) {
    int m = w * 32 + i * 8 + rsub;
    ga[i] = h + ((size_t)(r0 + m)) * DFF + kbeg + jsw;
    gb[i] = Wt2 + ((size_t)e * DM + n0 + m) * DFF + kbeg + jsw;
  }
  int ldsW = w * 2048 + lane * 8;

  int wm = w & 1, wn = w >> 1;
  int g = lane >> 4, l15 = lane & 15;
  int x7 = l15 & 7;
  int csel0 = (g ^ x7) * 8;
  int csel1 = ((4 + g) ^ x7) * 8;

  f32x4 acc[4][4];
#pragma unroll
  for (int i = 0; i < 4; ++i)
#pragma unroll
    for (int jj = 0; jj < 4; ++jj) acc[i][jj] = (f32x4){0.f, 0.f, 0.f, 0.f};

#pragma unroll
  for (int i = 0; i < 4; ++i) {
    load_lds16(ga[i], &As[ldsW + i * 512]);
    load_lds16(gb[i], &Bs[ldsW + i * 512]);
  }

  int buf = 0;
  const int NIT = (DFF / 2) / BK;  // 32
  for (int it = 0; it < NIT; ++it) {
    if (it + 1 < NIT) {
      int ko = (it + 1) * BK;
      int dst = (buf ^ 1) * 8192 + ldsW;
#pragma unroll
      for (int i = 0; i < 4; ++i) {
        load_lds16(ga[i] + ko, &As[dst + i * 512]);
        load_lds16(gb[i] + ko, &Bs[dst + i * 512]);
      }
      WAIT_VM8();
    } else {
      WAIT_VM0();
    }
    BARRIER();
    int bb = buf * 8192;
#pragma unroll
    for (int ks = 0; ks < 2; ++ks) {
      int cs = ks ? csel1 : csel0;
      short8 af[4], bfr[4];
#pragma unroll
      for (int mi = 0; mi < 4; ++mi)
        af[mi] = *(const short8*)&As[bb + (wm * 64 + mi * 16 + l15) * 64 + cs];
#pragma unroll
      for (int nj = 0; nj < 4; ++nj)
        bfr[nj] = *(const short8*)&Bs[bb + (wn * 64 + nj * 16 + l15) * 64 + cs];
#pragma unroll
      for (int mi = 0; mi < 4; ++mi)
#pragma unroll
        for (int nj = 0; nj < 4; ++nj)
          acc[mi][nj] = __builtin_amdgcn_mfma_f32_16x16x32_bf16(
              af[mi], bfr[nj], acc[mi][nj], 0, 0, 0);
    }
    BARRIER();
    buf ^= 1;
  }

  const float* b2e = b2 + (size_t)e * DM;
  float bscale = (z == 0) ? 1.f : 0.f;
  unsigned short* Sz = S + (size_t)z * PADCAP * DM;
#pragma unroll
  for (int nj = 0; nj < 4; ++nj) {
    int n = n0 + wn * 64 + nj * 16 + l15;
    float bv = b2e[n] * bscale;
#pragma unroll
    for (int mi = 0; mi < 4; ++mi) {
      int mb = r0 + wm * 64 + mi * 16 + g * 4;
#pragma unroll
      for (int r = 0; r < 4; ++r)
        Sz[(size_t)(mb + r) * DM + n] = f2bf(acc[mi][nj][r] + bv);
    }
  }
}

// ------- combine: out[t] = w0*(S0+S1)[slot0] + w1*(S0+S1)[slot1] ---------
__global__ __launch_bounds__(256) void combine_kernel(
    const unsigned short* __restrict__ S, const int* __restrict__ slot_of,
    const float* __restrict__ topk_w, float* __restrict__ out) {
  int gid = blockIdx.x * 256 + threadIdx.x;
  int t = gid >> 7;             // DM/8 = 128 chunks per token
  int c = (gid & 127) * 8;
  int s0 = slot_of[t * 2], s1 = slot_of[t * 2 + 1];
  float w0 = topk_w[t * 2], w1 = topk_w[t * 2 + 1];
  const short8 a0 = *(const short8*)(S + (size_t)s0 * DM + c);
  const short8 a1 = *(const short8*)(S + ((size_t)PADCAP + s0) * DM + c);
  const short8 b0 = *(const short8*)(S + (size_t)s1 * DM + c);
  const short8 b1 = *(const short8*)(S + ((size_t)PADCAP + s1) * DM + c);
  float o[8];
#pragma unroll
  for (int j = 0; j < 8; ++j) {
    float va = bf2f((unsigned short)a0[j]) + bf2f((unsigned short)a1[j]);
    float vb = bf2f((unsigned short)b0[j]) + bf2f((unsigned short)b1[j]);
    o[j] = w0 * va + w1 * vb;
  }
  float* op = out + (size_t)t * DM + c;
  *(float4*)op = (float4){o[0], o[1], o[2], o[3]};
  *(float4*)(op + 4) = (float4){o[4], o[5], o[6], o[7]};
}

extern "C" void kernel_launch(void* const* d_in, const int* in_sizes, int n_in,
                              void* d_out, int out_size, void* d_ws,
                              size_t ws_size, hipStream_t stream) {
  const float* x = (const float*)d_in[0];
  const float* Wg = (const float*)d_in[1];
  const float* W1 = (const float*)d_in[2];
  const float* b1 = (const float*)d_in[3];
  const float* W2 = (const float*)d_in[4];
  const float* b2 = (const float*)d_in[5];
  float* out = (float*)d_out;

  int* ws_i = (int*)d_ws;
  int* counts = ws_i;
  int* offsets = ws_i + 8;
  int* cursors = ws_i + 20;
  int* bucket_tok = ws_i + 32;                       // PADCAP
  int* topk_idx = ws_i + 32 + PADCAP;                // 2*T_TOK
  float* topk_w = (float*)(ws_i + 32 + PADCAP + 2 * T_TOK);
  int* slot_of = ws_i + 32 + PADCAP + 4 * T_TOK;     // 2*T_TOK

  const size_t XB_OFF = 1u << 20;
  const size_t WT_OFF = XB_OFF + (size_t)T_TOK * DM * 2;
  const size_t H_OFF = WT_OFF + (size_t)NE * DM * DFF * 2;
  const size_t S_OFF = H_OFF + (size_t)PADCAP * DFF * 2;
  unsigned short* xb = (unsigned short*)((char*)d_ws + XB_OFF);
  unsigned short* Wt = (unsigned short*)((char*)d_ws + WT_OFF);
  unsigned short* h = (unsigned short*)((char*)d_ws + H_OFF);
  unsigned short* S = (unsigned short*)((char*)d_ws + S_OFF);

  init_kernel<<<(PADCAP + 255) / 256, 256, 0, stream>>>(counts, cursors,
                                                        bucket_tok);
  gate_kernel<<<T_TOK / 4, 256, 0, stream>>>(x, Wg, counts, topk_idx, topk_w,
                                             xb);
  offsets_kernel<<<1, 64, 0, stream>>>(counts, offsets);
  scatter_kernel<<<T_TOK / 256, 256, 0, stream>>>(topk_idx, offsets, cursors,
                                                  bucket_tok, slot_of);
  transpose_cvt_kernel<<<dim3(DM / 64, DFF / 64, NE), 256, 0, stream>>>(
      W1, Wt, DM, DFF);
  gemm1_kernel<<<dim3(MTILES, DFF / 128), 256, 0, stream>>>(
      xb, Wt, b1, offsets, bucket_tok, h);
  transpose_cvt_kernel<<<dim3(DFF / 64, DM / 64, NE), 256, 0, stream>>>(
      W2, Wt, DFF, DM);
  gemm2_kernel<<<dim3(16, MTILES), 256, 0, stream>>>(h, Wt, b2, offsets, S);
  combine_kernel<<<(T_TOK * DM / 8) / 256, 256, 0, stream>>>(S, slot_of,
                                                             topk_w, out);
}